// Round 8
// baseline (443.520 us; speedup 1.0000x reference)
//
#include <hip/hip_runtime.h>

#define BB 128
#define TT 512
#define CC 128

typedef short short8 __attribute__((ext_vector_type(8)));
typedef float f32x4  __attribute__((ext_vector_type(4)));
typedef unsigned u32x4 __attribute__((ext_vector_type(4)));

__device__ __forceinline__ unsigned pk_trunc(float a, float b) {
    // lo16 = trunc-bf16(a), hi16 = trunc-bf16(b); single v_perm
    return __builtin_amdgcn_perm(__float_as_uint(a), __float_as_uint(b), 0x03020706u);
}
__device__ __forceinline__ unsigned short f2bf(float f) {   // RNE (A setup only)
    unsigned u = __float_as_uint(f);
    u += 0x7fffu + ((u >> 16) & 1u);
    return (unsigned short)(u >> 16);
}
__device__ __forceinline__ float lo16f(unsigned u) { return __uint_as_float(u << 16); }
__device__ __forceinline__ float hi16f(unsigned u) { return __uint_as_float(u & 0xffff0000u); }

#define MFMA16(A, B, C) __builtin_amdgcn_mfma_f32_16x16x32_bf16((A), (B), (C), 0, 0, 0)
#define LOG2E 1.442695041f

// Dual-group scan step: groups G0/G1 advance one step per barrier window.
// Per group: sigma'-permuted A (R7-verified) -> own block kt=w stays in BfO
// regs; other 3 blocks via staggered conflict-free ds_read_b128; one b128
// write. G1's instruction stream fills G0's latency stalls (R7 lesson:
// ~600 cyc/step was exposed latency, not LDS/issue).  Z4 = persistent zero
// C-operand (no per-step acc init). exp2f(x*mL) replaces expf(x*m).
// AP_ at t%4==1: pend from broadcast read of channel 0.
#define DOSTEP2(AP_, P_, RPAR_, TN_) do {                                      \
    const unsigned* sb0 = &sbuf[0][RPAR_][0];                                  \
    unsigned* sw0 = &sbuf[0][(RPAR_) ^ 1][0];                                  \
    const unsigned* sb1 = &sbuf[1][RPAR_][0];                                  \
    unsigned* sw1 = &sbuf[1][(RPAR_) ^ 1][0];                                  \
    u32x4 Rva1 = *(const u32x4*)(sb0 + rd1);                                   \
    u32x4 Rva2 = *(const u32x4*)(sb0 + rd2);                                   \
    u32x4 Rva3 = *(const u32x4*)(sb0 + rd3);                                   \
    u32x4 Rvb1 = *(const u32x4*)(sb1 + rd1);                                   \
    u32x4 Rvb2 = *(const u32x4*)(sb1 + rd2);                                   \
    u32x4 Rvb3 = *(const u32x4*)(sb1 + rd3);                                   \
    unsigned bcu0 = 0, bcu1 = 0;                                               \
    if (AP_) { bcu0 = sb0[bcaddr]; bcu1 = sb1[bcaddr]; }                       \
    const float mm0 = pfm0[P_], mm1 = pfm1[P_];                                \
    const float mL0 = mm0 * LOG2E, mL1 = mm1 * LOG2E;                          \
    float ea0[4], ea1[4], eb0[4], eb1[4];                                      \
    ea0[0] = exp2f(pfa0[P_].x * mL0); ea0[1] = exp2f(pfa0[P_].y * mL0);        \
    ea0[2] = exp2f(pfa0[P_].z * mL0); ea0[3] = exp2f(pfa0[P_].w * mL0);        \
    ea1[0] = exp2f(pfb0[P_].x * mL0); ea1[1] = exp2f(pfb0[P_].y * mL0);        \
    ea1[2] = exp2f(pfb0[P_].z * mL0); ea1[3] = exp2f(pfb0[P_].w * mL0);        \
    eb0[0] = exp2f(pfa1[P_].x * mL1); eb0[1] = exp2f(pfa1[P_].y * mL1);        \
    eb0[2] = exp2f(pfa1[P_].z * mL1); eb0[3] = exp2f(pfa1[P_].w * mL1);        \
    eb1[0] = exp2f(pfb1[P_].x * mL1); eb1[1] = exp2f(pfb1[P_].y * mL1);        \
    eb1[2] = exp2f(pfb1[P_].z * mL1); eb1[3] = exp2f(pfb1[P_].w * mL1);        \
    union { u32x4 u; short8 s; } cOa, ca1, ca2, ca3, cOb, cb1, cb2, cb3;       \
    cOa.u[0] = BfO0[0]; cOa.u[1] = BfO0[1];                                    \
    cOa.u[2] = BfO0[2]; cOa.u[3] = BfO0[3];                                    \
    cOb.u[0] = BfO1[0]; cOb.u[1] = BfO1[1];                                    \
    cOb.u[2] = BfO1[2]; cOb.u[3] = BfO1[3];                                    \
    ca1.u = Rva1; ca2.u = Rva2; ca3.u = Rva3;                                  \
    cb1.u = Rvb1; cb2.u = Rvb2; cb3.u = Rvb3;                                  \
    f32x4 aA0, aA1, aB0, aB1, bA0, bA1, bB0, bB1;                              \
    aA0 = MFMA16(AfP[0][0], cOa.s, Z4);  aA1 = MFMA16(AfP[1][0], cOa.s, Z4);   \
    bA0 = MFMA16(AfP[0][0], cOb.s, Z4);  bA1 = MFMA16(AfP[1][0], cOb.s, Z4);   \
    aA0 = MFMA16(AfP[0][1], ca1.s, aA0); aA1 = MFMA16(AfP[1][1], ca1.s, aA1);  \
    bA0 = MFMA16(AfP[0][1], cb1.s, bA0); bA1 = MFMA16(AfP[1][1], cb1.s, bA1);  \
    aB0 = MFMA16(AfP[0][2], ca2.s, Z4);  aB1 = MFMA16(AfP[1][2], ca2.s, Z4);   \
    bB0 = MFMA16(AfP[0][2], cb2.s, Z4);  bB1 = MFMA16(AfP[1][2], cb2.s, Z4);   \
    aB0 = MFMA16(AfP[0][3], ca3.s, aB0); aB1 = MFMA16(AfP[1][3], ca3.s, aB1);  \
    bB0 = MFMA16(AfP[0][3], cb3.s, bB0); bB1 = MFMA16(AfP[1][3], cb3.s, bB1);  \
    f32x4 ac0 = aA0 + aB0, ac1 = aA1 + aB1;                                    \
    f32x4 bc0 = bA0 + bB0, bc1 = bA1 + bB1;                                    \
    float pend0 = 1.f, pend1 = 1.f;                                            \
    if (AP_) {                                                                 \
        float v0_ = lo16f(bcu0), v1_ = lo16f(bcu1);                            \
        pend0 = __builtin_amdgcn_rcpf(v0_);                                    \
        pend1 = __builtin_amdgcn_rcpf(v1_);                                    \
        lacc0 += __logf(v0_); lacc1 += __logf(v1_);                            \
    }                                                                          \
    float v00 = ac0[0]*ea0[0], v01 = ac0[1]*ea0[1];                            \
    float v02 = ac0[2]*ea0[2], v03 = ac0[3]*ea0[3];                            \
    float v10 = ac1[0]*ea1[0], v11 = ac1[1]*ea1[1];                            \
    float v12 = ac1[2]*ea1[2], v13 = ac1[3]*ea1[3];                            \
    float w00 = bc0[0]*eb0[0], w01 = bc0[1]*eb0[1];                            \
    float w02 = bc0[2]*eb0[2], w03 = bc0[3]*eb0[3];                            \
    float w10 = bc1[0]*eb1[0], w11 = bc1[1]*eb1[1];                            \
    float w12 = bc1[2]*eb1[2], w13 = bc1[3]*eb1[3];                            \
    if (AP_) {                                                                 \
        v00 *= pend0; v01 *= pend0; v02 *= pend0; v03 *= pend0;                \
        v10 *= pend0; v11 *= pend0; v12 *= pend0; v13 *= pend0;                \
        w00 *= pend1; w01 *= pend1; w02 *= pend1; w03 *= pend1;                \
        w10 *= pend1; w11 *= pend1; w12 *= pend1; w13 *= pend1;                \
    }                                                                          \
    unsigned n0 = pk_trunc(v00, v01), n1 = pk_trunc(v02, v03);                 \
    unsigned n2 = pk_trunc(v10, v11), n3 = pk_trunc(v12, v13);                 \
    unsigned m0_ = pk_trunc(w00, w01), m1_ = pk_trunc(w02, w03);               \
    unsigned m2_ = pk_trunc(w10, w11), m3_ = pk_trunc(w12, w13);               \
    if (__ballot(mm0 <= 0.f)) {              /* rare keep-old (never hit) */   \
        unsigned k0 = pk_trunc(lo16f(BfO0[0]) * pend0, hi16f(BfO0[0]) * pend0);\
        unsigned k1 = pk_trunc(lo16f(BfO0[1]) * pend0, hi16f(BfO0[1]) * pend0);\
        unsigned k2 = pk_trunc(lo16f(BfO0[2]) * pend0, hi16f(BfO0[2]) * pend0);\
        unsigned k3 = pk_trunc(lo16f(BfO0[3]) * pend0, hi16f(BfO0[3]) * pend0);\
        const bool kk = (mm0 <= 0.f);                                          \
        n0 = kk ? k0 : n0; n1 = kk ? k1 : n1;                                  \
        n2 = kk ? k2 : n2; n3 = kk ? k3 : n3;                                  \
    }                                                                          \
    if (__ballot(mm1 <= 0.f)) {                                                \
        unsigned k0 = pk_trunc(lo16f(BfO1[0]) * pend1, hi16f(BfO1[0]) * pend1);\
        unsigned k1 = pk_trunc(lo16f(BfO1[1]) * pend1, hi16f(BfO1[1]) * pend1);\
        unsigned k2 = pk_trunc(lo16f(BfO1[2]) * pend1, hi16f(BfO1[2]) * pend1);\
        unsigned k3 = pk_trunc(lo16f(BfO1[3]) * pend1, hi16f(BfO1[3]) * pend1);\
        const bool kk = (mm1 <= 0.f);                                          \
        m0_ = kk ? k0 : m0_; m1_ = kk ? k1 : m1_;                              \
        m2_ = kk ? k2 : m2_; m3_ = kk ? k3 : m3_;                              \
    }                                                                          \
    u32x4 wva; wva[0] = n0;  wva[1] = n1;  wva[2] = n2;  wva[3] = n3;          \
    u32x4 wvb; wvb[0] = m0_; wvb[1] = m1_; wvb[2] = m2_; wvb[3] = m3_;         \
    *(u32x4*)(sw0 + wwOwn) = wva;                                              \
    *(u32x4*)(sw1 + wwOwn) = wvb;                                              \
    BfO0[0] = n0;  BfO0[1] = n1;  BfO0[2] = n2;  BfO0[3] = n3;                 \
    BfO1[0] = m0_; BfO1[1] = m1_; BfO1[2] = m2_; BfO1[3] = m3_;                \
    if ((TN_) >= 0) {                        /* depth-4 E prefetch, both */    \
        pfa0[P_] = *(const float4*)(yb0 + (size_t)(TN_) * CC + ch0p);          \
        pfb0[P_] = *(const float4*)(yb0 + (size_t)(TN_) * CC + ch0p + 4);      \
        pfm0[P_] = mrow0[TN_];                                                 \
        pfa1[P_] = *(const float4*)(yb1 + (size_t)(TN_) * CC + ch0p);          \
        pfb1[P_] = *(const float4*)(yb1 + (size_t)(TN_) * CC + ch0p + 4);      \
        pfm1[P_] = mrow1[TN_];                                                 \
    }                                                                          \
    asm volatile("s_waitcnt lgkmcnt(0)" ::: "memory");                         \
    __builtin_amdgcn_s_barrier();            /* raw: vm stays in flight */     \
    asm volatile("" ::: "memory");                                             \
} while (0)

// ---------------------------------------------------------------------------
// One fused kernel, 256 threads (4 waves).
// Blocks 0..3  : DUAL-group scan: block b advances groups 2b and 2b+1 one step
//                per barrier window, in the SAME waves (compile-time
//                interleave fills the ~600-cyc exposed latency of one group
//                with the other's instructions; 1 wave/SIMD and a 4-wave
//                barrier are preserved — the two things R2's failure had).
//                Shared Af; per-group LDS state + registers.
// Blocks 4..131: real-path score, 4 waves x 128 rows; atomicAdd(-score).
// ---------------------------------------------------------------------------
__global__ __launch_bounds__(256, 1) void crf_all(
    const float* __restrict__ y_true, const float* __restrict__ y_pred,
    const float* __restrict__ mask, const float* __restrict__ trans,
    float* __restrict__ out)
{
    __shared__ __align__(16) unsigned sbuf[2][2][1024];  // [group][buf] 16 KB
    __shared__ float red[2][4][16];

    const int tid  = threadIdx.x;
    const int lane = tid & 63;
    const int w    = tid >> 6;

    if (blockIdx.x >= 4) {
        // ===================== real path (verified core, 4x128) =============
        const int rb  = blockIdx.x - 4;
        const int ts  = w * 128;
        const int te  = min(ts + 128, TT - 1);
        const float* yt_b = y_true + (size_t)rb * TT * CC;
        const float* yp_b = y_pred + (size_t)rb * TT * CC;
        const float* m_b  = mask + (size_t)rb * TT;

        float em = 0.f, tr = 0.f;
        int lprev = 0; float mprev = 0.f;
        const float* ytr = yt_b + ts * CC;
        const float* ypr = yp_b + ts * CC;
        float cyt0 = ytr[lane], cyt1 = ytr[lane + 64];
        float cyp0 = ypr[lane], cyp1 = ypr[lane + 64];
        float cm = m_b[ts];
        for (int t = ts; t <= te; ++t) {
            float nyt0 = 0.f, nyt1 = 0.f, nyp0 = 0.f, nyp1 = 0.f, nm = 0.f;
            if (t < te) {
                const float* ytn = yt_b + (t + 1) * CC;
                const float* ypn = yp_b + (t + 1) * CC;
                nyt0 = ytn[lane]; nyt1 = ytn[lane + 64];
                nyp0 = ypn[lane]; nyp1 = ypn[lane + 64];
                nm = m_b[t + 1];
            }
            unsigned long long b0 = __ballot(cyt0 > 0.5f);
            unsigned long long b1 = __ballot(cyt1 > 0.5f);
            int l = b0 ? (__ffsll(b0) - 1) : (64 + __ffsll(b1) - 1);
            float v0 = __shfl(cyp0, l & 63);
            float v1 = __shfl(cyp1, l & 63);
            float v  = (l < 64) ? v0 : v1;
            if (lane == 0) {
                if (t < ts + 128) em += cm * cm * v;
                if (t > ts)       tr += mprev * cm * trans[lprev * CC + l];
            }
            lprev = l; mprev = cm;
            cyt0 = nyt0; cyt1 = nyt1; cyp0 = nyp0; cyp1 = nyp1; cm = nm;
        }
        if (lane == 0) atomicAdd(&out[rb], -(em + tr));
        return;
    }

    // ========================== dual-group scan ==========================
    const int bq = lane & 15;
    const int q  = lane >> 4;
    const int g0 = blockIdx.x * 2;
    const int g1 = g0 + 1;
    const float* yb0   = y_pred + (size_t)(g0 * 16 + bq) * TT * CC;
    const float* yb1   = y_pred + (size_t)(g1 * 16 + bq) * TT * CC;
    const float* mrow0 = mask + (size_t)(g0 * 16 + bq) * TT;
    const float* mrow1 = mask + (size_t)(g1 * 16 + bq) * TT;
    const int ch0p = 32 * w + 8 * q;         // lane's 8 channels: ch0p..ch0p+7

    // t=0 + depth-4 prefetch issued before A-frag math (both groups).
    const float4 i00 = *(const float4*)(yb0 + ch0p);
    const float4 i01 = *(const float4*)(yb0 + ch0p + 4);
    const float4 i10 = *(const float4*)(yb1 + ch0p);
    const float4 i11 = *(const float4*)(yb1 + ch0p + 4);
    const float  m00 = mrow0[0], m10 = mrow1[0];
    float4 pfa0[4], pfb0[4], pfa1[4], pfb1[4]; float pfm0[4], pfm1[4];
    #pragma unroll
    for (int p = 0; p < 4; ++p) {
        pfa0[p] = *(const float4*)(yb0 + (size_t)(1 + p) * CC + ch0p);
        pfb0[p] = *(const float4*)(yb0 + (size_t)(1 + p) * CC + ch0p + 4);
        pfm0[p] = mrow0[1 + p];
        pfa1[p] = *(const float4*)(yb1 + (size_t)(1 + p) * CC + ch0p);
        pfb1[p] = *(const float4*)(yb1 + (size_t)(1 + p) * CC + ch0p + 4);
        pfm1[p] = mrow1[1 + p];
    }

    // A-frags, sigma'-permuted + stagger (R7-verified), SHARED by both groups:
    // AfP[n2][i] = block kt=(w+i)&3, j = 32w + 8*(bq>>2) + 4*n2 + (bq&3).
    short8 AfP[2][4];
    #pragma unroll
    for (int n2 = 0; n2 < 2; ++n2) {
        const int j = 32 * w + 8 * (bq >> 2) + 4 * n2 + (bq & 3);
        #pragma unroll
        for (int i = 0; i < 4; ++i) {
            const int kt = (w + i) & 3;
            #pragma unroll
            for (int e = 0; e < 8; ++e)
                AfP[n2][i][e] = (short)f2bf(__expf(trans[(kt * 32 + q * 8 + e) * CC + j]));
        }
    }

    // LDS addressing (R7-verified): col bq at 64 words; pair P at (P ^ swz).
    const int swz = (bq & 7) << 2;
    const int rd1 = bq * 64 + ((((w + 1) & 3) * 16 + 4 * q) ^ swz);
    const int rd2 = bq * 64 + ((((w + 2) & 3) * 16 + 4 * q) ^ swz);
    const int rd3 = bq * 64 + ((((w + 3) & 3) * 16 + 4 * q) ^ swz);
    const int wwOwn = bq * 64 + ((16 * w + 4 * q) ^ swz);    // pairs 16w+4q..+3
    const int bcaddr = bq * 64 + swz;                        // pair 0 (channel 0)

    const f32x4 Z4 = {0.f, 0.f, 0.f, 0.f};   // persistent MFMA zero-C
    unsigned BfO0[4], BfO1[4];               // own blocks kt=w, in registers

    // t=0 init (both groups): state = exp(y_pred[:,0,:] * m0).
    {
        unsigned n0 = pk_trunc(__expf(i00.x * m00), __expf(i00.y * m00));
        unsigned n1 = pk_trunc(__expf(i00.z * m00), __expf(i00.w * m00));
        unsigned n2 = pk_trunc(__expf(i01.x * m00), __expf(i01.y * m00));
        unsigned n3 = pk_trunc(__expf(i01.z * m00), __expf(i01.w * m00));
        u32x4 wv; wv[0] = n0; wv[1] = n1; wv[2] = n2; wv[3] = n3;
        *(u32x4*)(&sbuf[0][0][0] + wwOwn) = wv;
        BfO0[0] = n0; BfO0[1] = n1; BfO0[2] = n2; BfO0[3] = n3;
        unsigned p0 = pk_trunc(__expf(i10.x * m10), __expf(i10.y * m10));
        unsigned p1 = pk_trunc(__expf(i10.z * m10), __expf(i10.w * m10));
        unsigned p2 = pk_trunc(__expf(i11.x * m10), __expf(i11.y * m10));
        unsigned p3 = pk_trunc(__expf(i11.z * m10), __expf(i11.w * m10));
        u32x4 wv2; wv2[0] = p0; wv2[1] = p1; wv2[2] = p2; wv2[3] = p3;
        *(u32x4*)(&sbuf[1][0][0] + wwOwn) = wv2;
        BfO1[0] = p0; BfO1[1] = p1; BfO1[2] = p2; BfO1[3] = p3;
    }
    asm volatile("s_waitcnt lgkmcnt(0)" ::: "memory");
    __builtin_amdgcn_s_barrier();
    asm volatile("" ::: "memory");

    float lacc0 = 0.f, lacc1 = 0.f;

    // steps 1..508 (127 chunks of 4; AP at t%4==1)
    for (int tt = 1; tt <= 505; tt += 4) {
        int t4 = tt + 4, t5 = tt + 5, t6 = tt + 6, t7 = tt + 7;
        if (t7 > TT - 1) t7 = TT - 1;        // only tt=505 clamps (512 -> 511)
        DOSTEP2(true,  0, 0, t4);
        DOSTEP2(false, 1, 1, t5);
        DOSTEP2(false, 2, 0, t6);
        DOSTEP2(false, 3, 1, t7);
    }
    // steps 509 (AP), 510
    DOSTEP2(true,  0, 0, -1);
    DOSTEP2(false, 1, 1, -1);

    // -------- step 511: final partial sums (pend == 1; reads buf 0) ---------
    #pragma unroll
    for (int h = 0; h < 2; ++h) {
        const unsigned* sb = &sbuf[h][0][0];
        u32x4 Rv1 = *(const u32x4*)(sb + rd1);
        u32x4 Rv2 = *(const u32x4*)(sb + rd2);
        u32x4 Rv3 = *(const u32x4*)(sb + rd3);
        const float mm = h ? pfm1[2] : pfm0[2];      // slot 2 holds t=511
        const float4 va = h ? pfa1[2] : pfa0[2];
        const float4 vb = h ? pfb1[2] : pfb0[2];
        const unsigned* BfO = h ? BfO1 : BfO0;
        const float mL = mm * LOG2E;
        float e0[4], e1[4];
        e0[0] = exp2f(va.x * mL); e0[1] = exp2f(va.y * mL);
        e0[2] = exp2f(va.z * mL); e0[3] = exp2f(va.w * mL);
        e1[0] = exp2f(vb.x * mL); e1[1] = exp2f(vb.y * mL);
        e1[2] = exp2f(vb.z * mL); e1[3] = exp2f(vb.w * mL);
        union { u32x4 u; short8 s; } cO, c1, c2, c3;
        cO.u[0] = BfO[0]; cO.u[1] = BfO[1]; cO.u[2] = BfO[2]; cO.u[3] = BfO[3];
        c1.u = Rv1; c2.u = Rv2; c3.u = Rv3;
        f32x4 aA0, aA1, aB0, aB1;
        aA0 = MFMA16(AfP[0][0], cO.s, Z4);   aA1 = MFMA16(AfP[1][0], cO.s, Z4);
        aA0 = MFMA16(AfP[0][1], c1.s, aA0);  aA1 = MFMA16(AfP[1][1], c1.s, aA1);
        aB0 = MFMA16(AfP[0][2], c2.s, Z4);   aB1 = MFMA16(AfP[1][2], c2.s, Z4);
        aB0 = MFMA16(AfP[0][3], c3.s, aB0);  aB1 = MFMA16(AfP[1][3], c3.s, aB1);
        f32x4 ac0 = aA0 + aB0, ac1 = aA1 + aB1;
        float ssum = ac0[0]*e0[0] + ac0[1]*e0[1] + ac0[2]*e0[2] + ac0[3]*e0[3]
                   + ac1[0]*e1[0] + ac1[1]*e1[1] + ac1[2]*e1[2] + ac1[3]*e1[3];
        if (__ballot(mm <= 0.f)) {           // pend == 1 here (511 % 4 == 3)
            float os = lo16f(BfO[0]) + hi16f(BfO[0]) + lo16f(BfO[1]) + hi16f(BfO[1])
                     + lo16f(BfO[2]) + hi16f(BfO[2]) + lo16f(BfO[3]) + hi16f(BfO[3]);
            ssum = (mm <= 0.f) ? os : ssum;
        }
        ssum += __shfl_xor(ssum, 16, 64);
        ssum += __shfl_xor(ssum, 32, 64);
        if (lane < 16) red[h][w][lane] = ssum;
    }
    asm volatile("s_waitcnt lgkmcnt(0)" ::: "memory");
    __builtin_amdgcn_s_barrier();
    asm volatile("" ::: "memory");
    if (w == 0 && lane < 16) {
        float tot0 = red[0][0][lane] + red[0][1][lane]
                   + red[0][2][lane] + red[0][3][lane];
        float tot1 = red[1][0][lane] + red[1][1][lane]
                   + red[1][2][lane] + red[1][3][lane];
        atomicAdd(&out[g0 * 16 + lane], __logf(tot0) + lacc0);
        atomicAdd(&out[g1 * 16 + lane], __logf(tot1) + lacc1);
    }
}

// ---------------------------------------------------------------------------
extern "C" void kernel_launch(void* const* d_in, const int* in_sizes, int n_in,
                              void* d_out, int out_size, void* d_ws, size_t ws_size,
                              hipStream_t stream) {
    (void)in_sizes; (void)n_in; (void)out_size; (void)d_ws; (void)ws_size;
    const float* y_true = (const float*)d_in[0];
    const float* y_pred = (const float*)d_in[1];
    const float* mask   = (const float*)d_in[2];
    const float* trans  = (const float*)d_in[3];
    float* out = (float*)d_out;

    hipMemsetAsync(out, 0, BB * sizeof(float), stream);
    crf_all<<<dim3(4 + BB), 256, 0, stream>>>(y_true, y_pred, mask, trans, out);
}

// Round 10
// 330.170 us; speedup vs baseline: 1.3433x; 1.3433x over previous
//
#include <hip/hip_runtime.h>

#define BB 128
#define TT 512
#define CC 128

typedef short short8 __attribute__((ext_vector_type(8)));
typedef float f32x4  __attribute__((ext_vector_type(4)));
typedef unsigned u32x4 __attribute__((ext_vector_type(4)));

__device__ __forceinline__ unsigned pk_trunc(float a, float b) {
    // lo16 = trunc-bf16(a), hi16 = trunc-bf16(b); single v_perm
    return __builtin_amdgcn_perm(__float_as_uint(a), __float_as_uint(b), 0x03020706u);
}
__device__ __forceinline__ unsigned short f2bf(float f) {   // RNE (A setup only)
    unsigned u = __float_as_uint(f);
    u += 0x7fffu + ((u >> 16) & 1u);
    return (unsigned short)(u >> 16);
}
__device__ __forceinline__ float lo16f(unsigned u) { return __uint_as_float(u << 16); }
__device__ __forceinline__ float hi16f(unsigned u) { return __uint_as_float(u & 0xffff0000u); }

#define MFMA16(A, B, C) __builtin_amdgcn_mfma_f32_16x16x32_bf16((A), (B), (C), 0, 0, 0)
#define LOG2E 1.442695041f

// One scan step (R7-verified core). R9 scheduling edits:
//  - prefetch issued BEFORE the MFMA cluster (VMEM issue overlaps MFMA);
//  - AP: pend computed early and folded into e (shorter post-MFMA tail);
//  - 1-deep MFMA accs from persistent Z4 + f32x4 add tree (one less
//    MFMA-dependency level on the critical path).
// sigma'-permuted A: lane (bq,q) outputs = its OWN next-step B-frag block
// kt=w (stays in BfO regs); other 3 blocks via staggered conflict-free
// ds_read_b128; one b128 write; raw s_barrier + lgkmcnt(0) (vm in flight).
#define DOSTEP(AP_, P_, RPAR_, TN_) do {                                       \
    const unsigned* sb = &sbuf[RPAR_][0];                                      \
    unsigned* sw = &sbuf[(RPAR_) ^ 1][0];                                      \
    u32x4 Rv1 = *(const u32x4*)(sb + rd1);                                     \
    u32x4 Rv2 = *(const u32x4*)(sb + rd2);                                     \
    u32x4 Rv3 = *(const u32x4*)(sb + rd3);                                     \
    unsigned bcu = 0;                                                          \
    if (AP_) bcu = sb[bcaddr];               /* pair 0 broadcast (ch 0) */     \
    const float mm = pfm[P_];                                                  \
    const float mL = mm * LOG2E;                                               \
    float e0[4], e1[4];                                                        \
    e0[0] = exp2f(pfa[P_].x * mL); e0[1] = exp2f(pfa[P_].y * mL);              \
    e0[2] = exp2f(pfa[P_].z * mL); e0[3] = exp2f(pfa[P_].w * mL);              \
    e1[0] = exp2f(pfb[P_].x * mL); e1[1] = exp2f(pfb[P_].y * mL);              \
    e1[2] = exp2f(pfb[P_].z * mL); e1[3] = exp2f(pfb[P_].w * mL);              \
    float pend = 1.f;                                                          \
    if (AP_) {                               /* early: fold pend into e */     \
        float bc = lo16f(bcu);                                                 \
        pend = __builtin_amdgcn_rcpf(bc);                                      \
        lacc += __logf(bc);                                                    \
        e0[0] *= pend; e0[1] *= pend; e0[2] *= pend; e0[3] *= pend;            \
        e1[0] *= pend; e1[1] *= pend; e1[2] *= pend; e1[3] *= pend;            \
    }                                                                          \
    if ((TN_) >= 0) {                        /* depth-4 E prefetch, EARLY */   \
        pfa[P_] = *(const float4*)(yb + (size_t)(TN_) * CC + ch0p);            \
        pfb[P_] = *(const float4*)(yb + (size_t)(TN_) * CC + ch0p + 4);        \
        pfm[P_] = mrow[TN_];                                                   \
    }                                                                          \
    union { u32x4 u; short8 s; } cO, c1, c2, c3;                               \
    cO.u[0] = BfO[0]; cO.u[1] = BfO[1]; cO.u[2] = BfO[2]; cO.u[3] = BfO[3];    \
    c1.u = Rv1; c2.u = Rv2; c3.u = Rv3;                                        \
    f32x4 aA0 = MFMA16(AfP[0][0], cO.s, Z4);                                   \
    f32x4 aA1 = MFMA16(AfP[1][0], cO.s, Z4);                                   \
    f32x4 aB0 = MFMA16(AfP[0][1], c1.s, Z4);                                   \
    f32x4 aB1 = MFMA16(AfP[1][1], c1.s, Z4);                                   \
    f32x4 aC0 = MFMA16(AfP[0][2], c2.s, Z4);                                   \
    f32x4 aC1 = MFMA16(AfP[1][2], c2.s, Z4);                                   \
    f32x4 aD0 = MFMA16(AfP[0][3], c3.s, Z4);                                   \
    f32x4 aD1 = MFMA16(AfP[1][3], c3.s, Z4);                                   \
    f32x4 ac0 = (aA0 + aB0) + (aC0 + aD0);                                     \
    f32x4 ac1 = (aA1 + aB1) + (aC1 + aD1);                                     \
    float v00 = ac0[0]*e0[0], v01 = ac0[1]*e0[1];                              \
    float v02 = ac0[2]*e0[2], v03 = ac0[3]*e0[3];                              \
    float v10 = ac1[0]*e1[0], v11 = ac1[1]*e1[1];                              \
    float v12 = ac1[2]*e1[2], v13 = ac1[3]*e1[3];                              \
    unsigned n0 = pk_trunc(v00, v01), n1 = pk_trunc(v02, v03);                 \
    unsigned n2 = pk_trunc(v10, v11), n3 = pk_trunc(v12, v13);                 \
    if (__ballot(mm <= 0.f)) {               /* rare keep-old (never hit) */   \
        unsigned k0 = pk_trunc(lo16f(BfO[0]) * pend, hi16f(BfO[0]) * pend);    \
        unsigned k1 = pk_trunc(lo16f(BfO[1]) * pend, hi16f(BfO[1]) * pend);    \
        unsigned k2 = pk_trunc(lo16f(BfO[2]) * pend, hi16f(BfO[2]) * pend);    \
        unsigned k3 = pk_trunc(lo16f(BfO[3]) * pend, hi16f(BfO[3]) * pend);    \
        const bool kk = (mm <= 0.f);                                           \
        n0 = kk ? k0 : n0; n1 = kk ? k1 : n1;                                  \
        n2 = kk ? k2 : n2; n3 = kk ? k3 : n3;                                  \
    }                                                                          \
    u32x4 wv; wv[0] = n0; wv[1] = n1; wv[2] = n2; wv[3] = n3;                  \
    *(u32x4*)(sw + wwOwn) = wv;              /* one b128, conflict-free */     \
    BfO[0] = n0; BfO[1] = n1; BfO[2] = n2; BfO[3] = n3;                        \
    asm volatile("s_waitcnt lgkmcnt(0)" ::: "memory");                         \
    __builtin_amdgcn_s_barrier();            /* raw: vm stays in flight */     \
    asm volatile("" ::: "memory");                                             \
} while (0)

// ---------------------------------------------------------------------------
// One fused kernel, 256 threads (4 waves).
// Blocks 0..7  : scan group g, 4 consumer waves; wave w owns channels
//                [32w,32w+32). R8 lesson: wall = 511 x window-time no matter
//                how many groups share a window — only the single chain's
//                per-step time matters. This round shaves its tail.
// Blocks 8..135: real-path score, 4 waves x 128 rows; atomicAdd(-score).
// ---------------------------------------------------------------------------
__global__ __launch_bounds__(256, 1) void crf_all(
    const float* __restrict__ y_true, const float* __restrict__ y_pred,
    const float* __restrict__ mask, const float* __restrict__ trans,
    float* __restrict__ out)
{
    __shared__ __align__(16) unsigned sbuf[2][1024];   // 8 KB double-buffered state
    __shared__ float red[4][16];

    const int tid  = threadIdx.x;
    const int lane = tid & 63;
    const int w    = tid >> 6;

    if (blockIdx.x >= 8) {
        // ===================== real path (verified core, 4x128) =============
        const int rb  = blockIdx.x - 8;
        const int ts  = w * 128;
        const int te  = min(ts + 128, TT - 1);
        const float* yt_b = y_true + (size_t)rb * TT * CC;
        const float* yp_b = y_pred + (size_t)rb * TT * CC;
        const float* m_b  = mask + (size_t)rb * TT;

        float em = 0.f, tr = 0.f;
        int lprev = 0; float mprev = 0.f;
        const float* ytr = yt_b + ts * CC;
        const float* ypr = yp_b + ts * CC;
        float cyt0 = ytr[lane], cyt1 = ytr[lane + 64];
        float cyp0 = ypr[lane], cyp1 = ypr[lane + 64];
        float cm = m_b[ts];
        for (int t = ts; t <= te; ++t) {
            float nyt0 = 0.f, nyt1 = 0.f, nyp0 = 0.f, nyp1 = 0.f, nm = 0.f;
            if (t < te) {
                const float* ytn = yt_b + (t + 1) * CC;
                const float* ypn = yp_b + (t + 1) * CC;
                nyt0 = ytn[lane]; nyt1 = ytn[lane + 64];
                nyp0 = ypn[lane]; nyp1 = ypn[lane + 64];
                nm = m_b[t + 1];
            }
            unsigned long long b0 = __ballot(cyt0 > 0.5f);
            unsigned long long b1 = __ballot(cyt1 > 0.5f);
            int l = b0 ? (__ffsll(b0) - 1) : (64 + __ffsll(b1) - 1);
            float v0 = __shfl(cyp0, l & 63);
            float v1 = __shfl(cyp1, l & 63);
            float v  = (l < 64) ? v0 : v1;
            if (lane == 0) {
                if (t < ts + 128) em += cm * cm * v;
                if (t > ts)       tr += mprev * cm * trans[lprev * CC + l];
            }
            lprev = l; mprev = cm;
            cyt0 = nyt0; cyt1 = nyt1; cyp0 = nyp0; cyp1 = nyp1; cm = nm;
        }
        if (lane == 0) atomicAdd(&out[rb], -(em + tr));
        return;
    }

    // ========================== scan blocks ==========================
    const int bq = lane & 15;
    const int q  = lane >> 4;
    const int g  = blockIdx.x;
    const float* yb   = y_pred + (size_t)(g * 16 + bq) * TT * CC;
    const float* mrow = mask + (size_t)(g * 16 + bq) * TT;
    const int ch0p = 32 * w + 8 * q;         // lane's 8 channels: ch0p..ch0p+7

    // t=0 + depth-4 prefetch issued before A-frag math.
    const float4 i0 = *(const float4*)(yb + ch0p);
    const float4 i1 = *(const float4*)(yb + ch0p + 4);
    const float  m0 = mrow[0];
    float4 pfa[4], pfb[4]; float pfm[4];
    #pragma unroll
    for (int p = 0; p < 4; ++p) {
        pfa[p] = *(const float4*)(yb + (size_t)(1 + p) * CC + ch0p);
        pfb[p] = *(const float4*)(yb + (size_t)(1 + p) * CC + ch0p + 4);
        pfm[p] = mrow[1 + p];
    }

    // A-frags, sigma'-permuted + stagger (R7-verified): AfP[n2][i] = block
    // kt=(w+i)&3, j = 32w + 8*(bq>>2) + 4*n2 + (bq&3).
    short8 AfP[2][4];
    #pragma unroll
    for (int n2 = 0; n2 < 2; ++n2) {
        const int j = 32 * w + 8 * (bq >> 2) + 4 * n2 + (bq & 3);
        #pragma unroll
        for (int i = 0; i < 4; ++i) {
            const int kt = (w + i) & 3;
            #pragma unroll
            for (int e = 0; e < 8; ++e)
                AfP[n2][i][e] = (short)f2bf(__expf(trans[(kt * 32 + q * 8 + e) * CC + j]));
        }
    }

    // LDS addressing (R7-verified): col bq at 64 words; pair P at (P ^ swz),
    // swz = (bq&7)<<2. All accesses b128 at (16*kt+4q)^swz: 8 words/bank.
    const int swz = (bq & 7) << 2;
    const int rd1 = bq * 64 + ((((w + 1) & 3) * 16 + 4 * q) ^ swz);
    const int rd2 = bq * 64 + ((((w + 2) & 3) * 16 + 4 * q) ^ swz);
    const int rd3 = bq * 64 + ((((w + 3) & 3) * 16 + 4 * q) ^ swz);
    const int wwOwn = bq * 64 + ((16 * w + 4 * q) ^ swz);    // pairs 16w+4q..+3
    const int bcaddr = bq * 64 + swz;                        // pair 0 (channel 0)

    const f32x4 Z4 = {0.f, 0.f, 0.f, 0.f};   // persistent MFMA zero-C
    unsigned BfO[4];                         // own block kt=w (= lane's pairs)

    // t=0 init: state = exp(y_pred[:,0,:] * m0); lane packs its own 4 pairs.
    {
        unsigned n0 = pk_trunc(__expf(i0.x * m0), __expf(i0.y * m0));
        unsigned n1 = pk_trunc(__expf(i0.z * m0), __expf(i0.w * m0));
        unsigned n2 = pk_trunc(__expf(i1.x * m0), __expf(i1.y * m0));
        unsigned n3 = pk_trunc(__expf(i1.z * m0), __expf(i1.w * m0));
        u32x4 wv; wv[0] = n0; wv[1] = n1; wv[2] = n2; wv[3] = n3;
        *(u32x4*)(&sbuf[0][0] + wwOwn) = wv;
        BfO[0] = n0; BfO[1] = n1; BfO[2] = n2; BfO[3] = n3;
    }
    asm volatile("s_waitcnt lgkmcnt(0)" ::: "memory");
    __builtin_amdgcn_s_barrier();
    asm volatile("" ::: "memory");

    float lacc = 0.f;

    // steps 1..508 (127 chunks of 4; AP at t%4==1)
    for (int tt = 1; tt <= 505; tt += 4) {
        int t4 = tt + 4, t5 = tt + 5, t6 = tt + 6, t7 = tt + 7;
        if (t7 > TT - 1) t7 = TT - 1;        // only tt=505 clamps (512 -> 511)
        DOSTEP(true,  0, 0, t4);
        DOSTEP(false, 1, 1, t5);
        DOSTEP(false, 2, 0, t6);
        DOSTEP(false, 3, 1, t7);
    }
    // steps 509 (AP), 510
    DOSTEP(true,  0, 0, -1);
    DOSTEP(false, 1, 1, -1);

    // -------- step 511: final partial sum (pend == 1; reads buf 0) ----------
    {
        const unsigned* sb = &sbuf[0][0];
        u32x4 Rv1 = *(const u32x4*)(sb + rd1);
        u32x4 Rv2 = *(const u32x4*)(sb + rd2);
        u32x4 Rv3 = *(const u32x4*)(sb + rd3);
        const float mm = pfm[2];             // slot 2 holds t=511
        const float mL = mm * LOG2E;
        float e0[4], e1[4];
        e0[0] = exp2f(pfa[2].x * mL); e0[1] = exp2f(pfa[2].y * mL);
        e0[2] = exp2f(pfa[2].z * mL); e0[3] = exp2f(pfa[2].w * mL);
        e1[0] = exp2f(pfb[2].x * mL); e1[1] = exp2f(pfb[2].y * mL);
        e1[2] = exp2f(pfb[2].z * mL); e1[3] = exp2f(pfb[2].w * mL);
        union { u32x4 u; short8 s; } cO, c1, c2, c3;
        cO.u[0] = BfO[0]; cO.u[1] = BfO[1]; cO.u[2] = BfO[2]; cO.u[3] = BfO[3];
        c1.u = Rv1; c2.u = Rv2; c3.u = Rv3;
        f32x4 aA0 = MFMA16(AfP[0][0], cO.s, Z4);
        f32x4 aA1 = MFMA16(AfP[1][0], cO.s, Z4);
        f32x4 aB0 = MFMA16(AfP[0][1], c1.s, Z4);
        f32x4 aB1 = MFMA16(AfP[1][1], c1.s, Z4);
        f32x4 aC0 = MFMA16(AfP[0][2], c2.s, Z4);
        f32x4 aC1 = MFMA16(AfP[1][2], c2.s, Z4);
        f32x4 aD0 = MFMA16(AfP[0][3], c3.s, Z4);
        f32x4 aD1 = MFMA16(AfP[1][3], c3.s, Z4);
        f32x4 ac0 = (aA0 + aB0) + (aC0 + aD0);
        f32x4 ac1 = (aA1 + aB1) + (aC1 + aD1);
        float ssum = ac0[0]*e0[0] + ac0[1]*e0[1] + ac0[2]*e0[2] + ac0[3]*e0[3]
                   + ac1[0]*e1[0] + ac1[1]*e1[1] + ac1[2]*e1[2] + ac1[3]*e1[3];
        if (__ballot(mm <= 0.f)) {           // pend == 1 here (511 % 4 == 3)
            float os = lo16f(BfO[0]) + hi16f(BfO[0]) + lo16f(BfO[1]) + hi16f(BfO[1])
                     + lo16f(BfO[2]) + hi16f(BfO[2]) + lo16f(BfO[3]) + hi16f(BfO[3]);
            ssum = (mm <= 0.f) ? os : ssum;
        }
        ssum += __shfl_xor(ssum, 16, 64);
        ssum += __shfl_xor(ssum, 32, 64);
        if (lane < 16) red[w][lane] = ssum;
        asm volatile("s_waitcnt lgkmcnt(0)" ::: "memory");
        __builtin_amdgcn_s_barrier();
        asm volatile("" ::: "memory");
        if (w == 0 && lane < 16) {
            float tot = red[0][lane] + red[1][lane] + red[2][lane] + red[3][lane];
            atomicAdd(&out[g * 16 + lane], __logf(tot) + lacc);
        }
    }
}

// ---------------------------------------------------------------------------
extern "C" void kernel_launch(void* const* d_in, const int* in_sizes, int n_in,
                              void* d_out, int out_size, void* d_ws, size_t ws_size,
                              hipStream_t stream) {
    (void)in_sizes; (void)n_in; (void)out_size; (void)d_ws; (void)ws_size;
    const float* y_true = (const float*)d_in[0];
    const float* y_pred = (const float*)d_in[1];
    const float* mask   = (const float*)d_in[2];
    const float* trans  = (const float*)d_in[3];
    float* out = (float*)d_out;

    hipMemsetAsync(out, 0, BB * sizeof(float), stream);
    crf_all<<<dim3(8 + BB), 256, 0, stream>>>(y_true, y_pred, mask, trans, out);
}

// Round 11
// 252.872 us; speedup vs baseline: 1.7539x; 1.3057x over previous
//
#include <hip/hip_runtime.h>

#define BB 128
#define TT 512
#define CC 128

typedef short short8 __attribute__((ext_vector_type(8)));
typedef float f32x4  __attribute__((ext_vector_type(4)));
typedef unsigned u32x4 __attribute__((ext_vector_type(4)));

__device__ __forceinline__ unsigned pk_trunc(float a, float b) {
    // lo16 = trunc-bf16(a), hi16 = trunc-bf16(b); single v_perm
    return __builtin_amdgcn_perm(__float_as_uint(a), __float_as_uint(b), 0x03020706u);
}
__device__ __forceinline__ unsigned short f2bf(float f) {   // RNE (A setup only)
    unsigned u = __float_as_uint(f);
    u += 0x7fffu + ((u >> 16) & 1u);
    return (unsigned short)(u >> 16);
}
__device__ __forceinline__ float lo16f(unsigned u) { return __uint_as_float(u << 16); }
__device__ __forceinline__ float hi16f(unsigned u) { return __uint_as_float(u & 0xffff0000u); }

#define MFMA16(A, B, C) __builtin_amdgcn_mfma_f32_16x16x32_bf16((A), (B), (C), 0, 0, 0)

// One scan step. sigma'-permuted A (R4-verified family): lane (bq,q) outputs
// channels 32w+8q+{0..7} = pairs 16w+4q+{0..3} = its OWN next-step B-frag
// block kt=w -> own block stays in BfO regs (no LDS read, no shfl), write is
// ONE b128 at the conflict-free (16w+4q)^swz pattern, keep-old uses BfO.
// AP_ at t%4==1: pend from broadcast read of channel 0 (R6-verified bcaddr).
// R10 lesson: accumulate-dependent MFMAs run at issue rate (no removable
// latency level); every reshuffle of this schedule regressed. Keep exactly.
#define DOSTEP(AP_, P_, RPAR_, TN_) do {                                       \
    const unsigned* sb = &sbuf[RPAR_][0];                                      \
    unsigned* sw = &sbuf[(RPAR_) ^ 1][0];                                      \
    u32x4 Rv1 = *(const u32x4*)(sb + rd1);                                     \
    u32x4 Rv2 = *(const u32x4*)(sb + rd2);                                     \
    u32x4 Rv3 = *(const u32x4*)(sb + rd3);                                     \
    unsigned bcu = 0;                                                          \
    if (AP_) bcu = sb[bcaddr];               /* pair 0 broadcast (ch 0) */     \
    const float mm = pfm[P_];                                                  \
    float e0[4], e1[4];                                                        \
    e0[0] = __expf(pfa[P_].x * mm); e0[1] = __expf(pfa[P_].y * mm);            \
    e0[2] = __expf(pfa[P_].z * mm); e0[3] = __expf(pfa[P_].w * mm);            \
    e1[0] = __expf(pfb[P_].x * mm); e1[1] = __expf(pfb[P_].y * mm);            \
    e1[2] = __expf(pfb[P_].z * mm); e1[3] = __expf(pfb[P_].w * mm);            \
    union { u32x4 u; short8 s; } cO, c1, c2, c3;                               \
    cO.u[0] = BfO[0]; cO.u[1] = BfO[1]; cO.u[2] = BfO[2]; cO.u[3] = BfO[3];    \
    c1.u = Rv1; c2.u = Rv2; c3.u = Rv3;                                        \
    f32x4 aA0 = {0.f,0.f,0.f,0.f}, aA1 = {0.f,0.f,0.f,0.f};                    \
    f32x4 aB0 = {0.f,0.f,0.f,0.f}, aB1 = {0.f,0.f,0.f,0.f};                    \
    aA0 = MFMA16(AfP[0][0], cO.s, aA0);  aA1 = MFMA16(AfP[1][0], cO.s, aA1);   \
    aA0 = MFMA16(AfP[0][1], c1.s, aA0);  aA1 = MFMA16(AfP[1][1], c1.s, aA1);   \
    aB0 = MFMA16(AfP[0][2], c2.s, aB0);  aB1 = MFMA16(AfP[1][2], c2.s, aB1);   \
    aB0 = MFMA16(AfP[0][3], c3.s, aB0);  aB1 = MFMA16(AfP[1][3], c3.s, aB1);   \
    f32x4 ac0 = aA0 + aB0, ac1 = aA1 + aB1;                                    \
    float pend = 1.f;                                                          \
    if (AP_) {                                                                 \
        float bc = lo16f(bcu);                                                 \
        pend = __builtin_amdgcn_rcpf(bc);                                      \
        lacc += __logf(bc);                                                    \
    }                                                                          \
    float v00 = ac0[0]*e0[0], v01 = ac0[1]*e0[1];                              \
    float v02 = ac0[2]*e0[2], v03 = ac0[3]*e0[3];                              \
    float v10 = ac1[0]*e1[0], v11 = ac1[1]*e1[1];                              \
    float v12 = ac1[2]*e1[2], v13 = ac1[3]*e1[3];                              \
    if (AP_) {                                                                 \
        v00 *= pend; v01 *= pend; v02 *= pend; v03 *= pend;                    \
        v10 *= pend; v11 *= pend; v12 *= pend; v13 *= pend;                    \
    }                                                                          \
    unsigned n0 = pk_trunc(v00, v01), n1 = pk_trunc(v02, v03);                 \
    unsigned n2 = pk_trunc(v10, v11), n3 = pk_trunc(v12, v13);                 \
    if (__ballot(mm <= 0.f)) {               /* rare keep-old (never hit) */   \
        unsigned k0 = pk_trunc(lo16f(BfO[0]) * pend, hi16f(BfO[0]) * pend);    \
        unsigned k1 = pk_trunc(lo16f(BfO[1]) * pend, hi16f(BfO[1]) * pend);    \
        unsigned k2 = pk_trunc(lo16f(BfO[2]) * pend, hi16f(BfO[2]) * pend);    \
        unsigned k3 = pk_trunc(lo16f(BfO[3]) * pend, hi16f(BfO[3]) * pend);    \
        const bool kk = (mm <= 0.f);                                           \
        n0 = kk ? k0 : n0; n1 = kk ? k1 : n1;                                  \
        n2 = kk ? k2 : n2; n3 = kk ? k3 : n3;                                  \
    }                                                                          \
    u32x4 wv; wv[0] = n0; wv[1] = n1; wv[2] = n2; wv[3] = n3;                  \
    *(u32x4*)(sw + wwOwn) = wv;              /* one b128, conflict-free */     \
    BfO[0] = n0; BfO[1] = n1; BfO[2] = n2; BfO[3] = n3;                        \
    if ((TN_) >= 0) {                        /* depth-4 E prefetch */          \
        pfa[P_] = *(const float4*)(yb + (size_t)(TN_) * CC + ch0p);            \
        pfb[P_] = *(const float4*)(yb + (size_t)(TN_) * CC + ch0p + 4);        \
        pfm[P_] = mrow[TN_];                                                   \
    }                                                                          \
    asm volatile("s_waitcnt lgkmcnt(0)" ::: "memory");                         \
    __builtin_amdgcn_s_barrier();            /* raw: vm stays in flight */     \
    asm volatile("" ::: "memory");                                             \
} while (0)

// ---------------------------------------------------------------------------
// One fused kernel, 256 threads (4 waves).
// Blocks 0..7  : scan group g, 4 consumer waves; wave w owns channels
//                [32w,32w+32). sigma'-permuted A makes each lane's outputs its
//                own next-step B-frag (register-resident own block); other 3
//                blocks via staggered conflict-free ds_read_b128; one b128
//                write; one raw s_barrier + lgkmcnt(0)/step (vm in flight).
// Blocks 8..135: real-path score, 4 waves x 128 rows; atomicAdd(-score).
// This is the verified-best R7 schedule (scan 172 us, wall 253.8 us).
// ---------------------------------------------------------------------------
__global__ __launch_bounds__(256, 1) void crf_all(
    const float* __restrict__ y_true, const float* __restrict__ y_pred,
    const float* __restrict__ mask, const float* __restrict__ trans,
    float* __restrict__ out)
{
    __shared__ __align__(16) unsigned sbuf[2][1024];   // 8 KB double-buffered state
    __shared__ float red[4][16];

    const int tid  = threadIdx.x;
    const int lane = tid & 63;
    const int w    = tid >> 6;

    if (blockIdx.x >= 8) {
        // ===================== real path (verified core, 4x128) =============
        const int rb  = blockIdx.x - 8;
        const int ts  = w * 128;
        const int te  = min(ts + 128, TT - 1);
        const float* yt_b = y_true + (size_t)rb * TT * CC;
        const float* yp_b = y_pred + (size_t)rb * TT * CC;
        const float* m_b  = mask + (size_t)rb * TT;

        float em = 0.f, tr = 0.f;
        int lprev = 0; float mprev = 0.f;
        const float* ytr = yt_b + ts * CC;
        const float* ypr = yp_b + ts * CC;
        float cyt0 = ytr[lane], cyt1 = ytr[lane + 64];
        float cyp0 = ypr[lane], cyp1 = ypr[lane + 64];
        float cm = m_b[ts];
        for (int t = ts; t <= te; ++t) {
            float nyt0 = 0.f, nyt1 = 0.f, nyp0 = 0.f, nyp1 = 0.f, nm = 0.f;
            if (t < te) {
                const float* ytn = yt_b + (t + 1) * CC;
                const float* ypn = yp_b + (t + 1) * CC;
                nyt0 = ytn[lane]; nyt1 = ytn[lane + 64];
                nyp0 = ypn[lane]; nyp1 = ypn[lane + 64];
                nm = m_b[t + 1];
            }
            unsigned long long b0 = __ballot(cyt0 > 0.5f);
            unsigned long long b1 = __ballot(cyt1 > 0.5f);
            int l = b0 ? (__ffsll(b0) - 1) : (64 + __ffsll(b1) - 1);
            float v0 = __shfl(cyp0, l & 63);
            float v1 = __shfl(cyp1, l & 63);
            float v  = (l < 64) ? v0 : v1;
            if (lane == 0) {
                if (t < ts + 128) em += cm * cm * v;
                if (t > ts)       tr += mprev * cm * trans[lprev * CC + l];
            }
            lprev = l; mprev = cm;
            cyt0 = nyt0; cyt1 = nyt1; cyp0 = nyp0; cyp1 = nyp1; cm = nm;
        }
        if (lane == 0) atomicAdd(&out[rb], -(em + tr));
        return;
    }

    // ========================== scan blocks ==========================
    const int bq = lane & 15;
    const int q  = lane >> 4;
    const int g  = blockIdx.x;
    const float* yb   = y_pred + (size_t)(g * 16 + bq) * TT * CC;
    const float* mrow = mask + (size_t)(g * 16 + bq) * TT;
    const int ch0p = 32 * w + 8 * q;         // lane's 8 channels: ch0p..ch0p+7

    // t=0 + depth-4 prefetch issued before A-frag math.
    const float4 i0 = *(const float4*)(yb + ch0p);
    const float4 i1 = *(const float4*)(yb + ch0p + 4);
    const float  m0 = mrow[0];
    float4 pfa[4], pfb[4]; float pfm[4];
    #pragma unroll
    for (int p = 0; p < 4; ++p) {
        pfa[p] = *(const float4*)(yb + (size_t)(1 + p) * CC + ch0p);
        pfb[p] = *(const float4*)(yb + (size_t)(1 + p) * CC + ch0p + 4);
        pfm[p] = mrow[1 + p];
    }

    // A-frags, sigma'-permuted + stagger: AfP[n2][i] = block kt=(w+i)&3,
    // A[row=bq][k=kt*32+8q+e] = expT[k][j], j = 32w + 8*(bq>>2) + 4*n2 + (bq&3).
    // => lane (bq,q) outputs channels 32w+8q+4*n2+r (r=acc reg) — its own
    //    next-step B-frag pairs 16w+4q+{0..3}. (sigma verified R0/R4.)
    short8 AfP[2][4];
    #pragma unroll
    for (int n2 = 0; n2 < 2; ++n2) {
        const int j = 32 * w + 8 * (bq >> 2) + 4 * n2 + (bq & 3);
        #pragma unroll
        for (int i = 0; i < 4; ++i) {
            const int kt = (w + i) & 3;
            #pragma unroll
            for (int e = 0; e < 8; ++e)
                AfP[n2][i][e] = (short)f2bf(__expf(trans[(kt * 32 + q * 8 + e) * CC + j]));
        }
    }

    // LDS layout (R1-verified): col bq at 64 words; pair P at word (P ^ swz),
    // swz = (bq&7)<<2. All accesses b128 at (16*kt+4q)^swz: 8 words/bank.
    const int swz = (bq & 7) << 2;
    const int rd1 = bq * 64 + ((((w + 1) & 3) * 16 + 4 * q) ^ swz);
    const int rd2 = bq * 64 + ((((w + 2) & 3) * 16 + 4 * q) ^ swz);
    const int rd3 = bq * 64 + ((((w + 3) & 3) * 16 + 4 * q) ^ swz);
    const int wwOwn = bq * 64 + ((16 * w + 4 * q) ^ swz);    // pairs 16w+4q..+3
    const int bcaddr = bq * 64 + swz;                        // pair 0 (channel 0)

    unsigned BfO[4];                         // own block kt=w (= lane's pairs)

    // t=0 init: state = exp(y_pred[:,0,:] * m0); lane packs its own 4 pairs.
    {
        unsigned n0 = pk_trunc(__expf(i0.x * m0), __expf(i0.y * m0));
        unsigned n1 = pk_trunc(__expf(i0.z * m0), __expf(i0.w * m0));
        unsigned n2 = pk_trunc(__expf(i1.x * m0), __expf(i1.y * m0));
        unsigned n3 = pk_trunc(__expf(i1.z * m0), __expf(i1.w * m0));
        u32x4 wv; wv[0] = n0; wv[1] = n1; wv[2] = n2; wv[3] = n3;
        *(u32x4*)(&sbuf[0][0] + wwOwn) = wv;
        BfO[0] = n0; BfO[1] = n1; BfO[2] = n2; BfO[3] = n3;
    }
    asm volatile("s_waitcnt lgkmcnt(0)" ::: "memory");
    __builtin_amdgcn_s_barrier();
    asm volatile("" ::: "memory");

    float lacc = 0.f;

    // steps 1..508 (127 chunks of 4; AP at t%4==1)
    for (int tt = 1; tt <= 505; tt += 4) {
        int t4 = tt + 4, t5 = tt + 5, t6 = tt + 6, t7 = tt + 7;
        if (t7 > TT - 1) t7 = TT - 1;        // only tt=505 clamps (512 -> 511)
        DOSTEP(true,  0, 0, t4);
        DOSTEP(false, 1, 1, t5);
        DOSTEP(false, 2, 0, t6);
        DOSTEP(false, 3, 1, t7);
    }
    // steps 509 (AP), 510
    DOSTEP(true,  0, 0, -1);
    DOSTEP(false, 1, 1, -1);

    // -------- step 511: final partial sum (pend == 1; reads buf 0) ----------
    {
        const unsigned* sb = &sbuf[0][0];
        u32x4 Rv1 = *(const u32x4*)(sb + rd1);
        u32x4 Rv2 = *(const u32x4*)(sb + rd2);
        u32x4 Rv3 = *(const u32x4*)(sb + rd3);
        const float mm = pfm[2];             // slot 2 holds t=511
        float e0[4], e1[4];
        e0[0] = __expf(pfa[2].x * mm); e0[1] = __expf(pfa[2].y * mm);
        e0[2] = __expf(pfa[2].z * mm); e0[3] = __expf(pfa[2].w * mm);
        e1[0] = __expf(pfb[2].x * mm); e1[1] = __expf(pfb[2].y * mm);
        e1[2] = __expf(pfb[2].z * mm); e1[3] = __expf(pfb[2].w * mm);
        union { u32x4 u; short8 s; } cO, c1, c2, c3;
        cO.u[0] = BfO[0]; cO.u[1] = BfO[1]; cO.u[2] = BfO[2]; cO.u[3] = BfO[3];
        c1.u = Rv1; c2.u = Rv2; c3.u = Rv3;
        f32x4 aA0 = {0.f,0.f,0.f,0.f}, aA1 = {0.f,0.f,0.f,0.f};
        f32x4 aB0 = {0.f,0.f,0.f,0.f}, aB1 = {0.f,0.f,0.f,0.f};
        aA0 = MFMA16(AfP[0][0], cO.s, aA0);  aA1 = MFMA16(AfP[1][0], cO.s, aA1);
        aA0 = MFMA16(AfP[0][1], c1.s, aA0);  aA1 = MFMA16(AfP[1][1], c1.s, aA1);
        aB0 = MFMA16(AfP[0][2], c2.s, aB0);  aB1 = MFMA16(AfP[1][2], c2.s, aB1);
        aB0 = MFMA16(AfP[0][3], c3.s, aB0);  aB1 = MFMA16(AfP[1][3], c3.s, aB1);
        f32x4 ac0 = aA0 + aB0, ac1 = aA1 + aB1;
        float ssum = ac0[0]*e0[0] + ac0[1]*e0[1] + ac0[2]*e0[2] + ac0[3]*e0[3]
                   + ac1[0]*e1[0] + ac1[1]*e1[1] + ac1[2]*e1[2] + ac1[3]*e1[3];
        if (__ballot(mm <= 0.f)) {           // pend == 1 here (511 % 4 == 3)
            float os = lo16f(BfO[0]) + hi16f(BfO[0]) + lo16f(BfO[1]) + hi16f(BfO[1])
                     + lo16f(BfO[2]) + hi16f(BfO[2]) + lo16f(BfO[3]) + hi16f(BfO[3]);
            ssum = (mm <= 0.f) ? os : ssum;
        }
        ssum += __shfl_xor(ssum, 16, 64);
        ssum += __shfl_xor(ssum, 32, 64);
        if (lane < 16) red[w][lane] = ssum;
        asm volatile("s_waitcnt lgkmcnt(0)" ::: "memory");
        __builtin_amdgcn_s_barrier();
        asm volatile("" ::: "memory");
        if (w == 0 && lane < 16) {
            float tot = red[0][lane] + red[1][lane] + red[2][lane] + red[3][lane];
            atomicAdd(&out[g * 16 + lane], __logf(tot) + lacc);
        }
    }
}

// ---------------------------------------------------------------------------
extern "C" void kernel_launch(void* const* d_in, const int* in_sizes, int n_in,
                              void* d_out, int out_size, void* d_ws, size_t ws_size,
                              hipStream_t stream) {
    (void)in_sizes; (void)n_in; (void)out_size; (void)d_ws; (void)ws_size;
    const float* y_true = (const float*)d_in[0];
    const float* y_pred = (const float*)d_in[1];
    const float* mask   = (const float*)d_in[2];
    const float* trans  = (const float*)d_in[3];
    float* out = (float*)d_out;

    hipMemsetAsync(out, 0, BB * sizeof(float), stream);
    crf_all<<<dim3(8 + BB), 256, 0, stream>>>(y_true, y_pred, mask, trans, out);
}